// Round 5
// baseline (246.857 us; speedup 1.0000x reference)
//
#include <hip/hip_runtime.h>
#include <hip/hip_bf16.h>

// DomainEncoder: 8-expert MoE MLP, N=32768, 256 -> 1024 (LN+ReLU) -> 256.
// Pipeline (7 launches):
//   1. transpose_both: W1,W2 -> bf16 [N,K] in one launch (z=0..15)
//   2. counting-sort rows: histo -> make_meta (parallel pad) -> assign_pos
//      -> copy_rows
//   3. gemm_a: 128x256 blocks, H = x_s @ W1[d]^T + b1 (bf16) + stats[8][MPAD]
//   4. gemm_b_ln: 128x256 (full DOUT) blocks; A-staging = LN+gamma/beta+ReLU
//      VGPR round-trip (gamma/beta in LDS bf16, H prefetched 1 step ahead);
//      out = g @ W2[d]^T + b2 scattered via perm (fp32)

#define ND 8
#define NROWS 32768
#define DIN 256
#define DHID 1024
#define DOUT 256
#define MPAD 33792          // 32768 + 8*128 worst-case padding
#define NTILES 264          // 256 + 8 worst-case 128-row tiles

typedef short short8 __attribute__((ext_vector_type(8)));
typedef unsigned short ushort8v __attribute__((ext_vector_type(8)));
typedef float floatx4 __attribute__((ext_vector_type(4)));

__device__ __forceinline__ unsigned short f2bf(float f) {
    unsigned u = __builtin_bit_cast(unsigned, f);
    unsigned r = u + 0x7fff + ((u >> 16) & 1);   // RNE (inputs finite)
    return (unsigned short)(r >> 16);
}
__device__ __forceinline__ float bf2f(unsigned short h) {
    unsigned u = ((unsigned)h) << 16;
    return __builtin_bit_cast(float, u);
}

#define GLDS16(gp, lp) __builtin_amdgcn_global_load_lds( \
    (const __attribute__((address_space(1))) void*)(gp), \
    (__attribute__((address_space(3))) void*)(lp), 16, 0, 0)

// ---------------- 1. both weight transposes in one launch --------------------
// z<8: W1 dom z (R=256,C=1024, r-tiles=bx, c-tiles=by); z>=8: W2 dom z-8
// (R=1024,C=256, r-tiles=by, c-tiles=bx). grid dim3(8,32,16).
__global__ void transpose_both(const float* __restrict__ W1,
                               const float* __restrict__ W2,
                               unsigned short* __restrict__ W1T,
                               unsigned short* __restrict__ W2T,
                               int* __restrict__ cnt) {
    __shared__ float t[32][33];
    const int z = blockIdx.z;
    const bool isW1 = z < ND;
    const int d = isW1 ? z : z - ND;
    const int R = isW1 ? DIN : DHID;
    const int C = isW1 ? DHID : DOUT;
    const int r0 = (isW1 ? blockIdx.x : blockIdx.y) * 32;
    const int c0 = (isW1 ? blockIdx.y : blockIdx.x) * 32;
    const int tx = threadIdx.x & 31, ty = threadIdx.x >> 5;   // 32x8
    if (z == 0 && blockIdx.x == 0 && blockIdx.y == 0 && threadIdx.x < 16)
        cnt[threadIdx.x] = 0;
    const float* src = (isW1 ? W1 : W2) + (size_t)d * R * C;
    unsigned short* dst = (isW1 ? W1T : W2T) + (size_t)d * R * C;
#pragma unroll
    for (int i = 0; i < 32; i += 8)
        t[ty + i][tx] = src[(size_t)(r0 + ty + i) * C + c0 + tx];
    __syncthreads();
#pragma unroll
    for (int i = 0; i < 32; i += 8)
        dst[(size_t)(c0 + ty + i) * R + r0 + tx] = f2bf(t[tx][ty + i]);
}

// ---------------- 2a. histogram (block-aggregated atomics) --------------------
__global__ void histo(const int* __restrict__ dt, int* __restrict__ counts) {
    __shared__ int lc[ND];
    if (threadIdx.x < ND) lc[threadIdx.x] = 0;
    __syncthreads();
    int i = blockIdx.x * 256 + threadIdx.x;      // grid covers exactly NROWS
    atomicAdd(&lc[dt[i]], 1);
    __syncthreads();
    if (threadIdx.x < ND) atomicAdd(&counts[threadIdx.x], lc[threadIdx.x]);
}

// ---------------- 2b. offsets + tile metadata + parallel perm pad -------------
__global__ void make_meta(const int* __restrict__ counts, int* __restrict__ cursors,
                          int2* __restrict__ meta, int* __restrict__ perm) {
    __shared__ int ps[ND], pe[ND];
    if (threadIdx.x == 0) {
        int off = 0, t = 0;
        for (int d = 0; d < ND; d++) {
            cursors[d] = off;
            int nt = (counts[d] + 127) >> 7;
            for (int i = 0; i < nt; i++) meta[t++] = make_int2(d, off + (i << 7));
            ps[d] = off + counts[d];
            pe[d] = off + (nt << 7);
            off += nt << 7;
        }
        for (; t < NTILES; t++) meta[t] = make_int2(-1, 0);
    }
    __syncthreads();
#pragma unroll
    for (int d = 0; d < ND; d++)
        for (int p = ps[d] + threadIdx.x; p < pe[d]; p += 256) perm[p] = -1;
}

// ---------------- 2c. position assignment: 8 global atomics per 256 rows ------
__global__ __launch_bounds__(256)
void assign_pos(const int* __restrict__ dt, int* __restrict__ cursors,
                int* __restrict__ perm, int* __restrict__ pos) {
    __shared__ int lcnt[ND];
    __shared__ int lbase[ND];
    const int tid = threadIdx.x;
    if (tid < ND) lcnt[tid] = 0;
    __syncthreads();
    const int r = blockIdx.x * 256 + tid;
    const int d = dt[r];
    const int myrank = atomicAdd(&lcnt[d], 1);   // LDS atomic: cheap
    __syncthreads();
    if (tid < ND && lcnt[tid] > 0)
        lbase[tid] = atomicAdd(&cursors[tid], lcnt[tid]);  // 8 global atomics/block
    __syncthreads();
    const int p = lbase[d] + myrank;
    pos[r] = p;
    perm[p] = r;
}

// ---------------- 2d. gather copy: one wave per row, coalesced ---------------
__global__ __launch_bounds__(256)
void copy_rows(const float* __restrict__ x, const int* __restrict__ pos,
               unsigned short* __restrict__ xs) {
    const int tid = threadIdx.x;
    const int lane = tid & 63;
    const int r = blockIdx.x * 4 + (tid >> 6);           // 4 rows per block
    const int p = pos[r];
    float4 v = ((const float4*)(x + (size_t)r * DIN))[lane];   // 16B/lane read
    ushort4 o;
    o.x = f2bf(v.x); o.y = f2bf(v.y); o.z = f2bf(v.z); o.w = f2bf(v.w);
    ((ushort4*)(xs + (size_t)p * DIN))[lane] = o;              // 8B/lane write
}

// ---------------- 3. GEMM-A: 128x256 block, bias + per-row stats -------------
// 4 waves in 2x2; wave tile 64 rows x 128 cols = 4x8 mfma_16x16x32_bf16.
// stats slab = blockIdx.y*2 + wc (8 slabs); each slot written exactly once.
__global__ __launch_bounds__(256, 2)
void gemm_a(const unsigned short* __restrict__ A,      // XS [MPAD,256]
            const unsigned short* __restrict__ Bt,     // W1T [ND,1024,256]
            const float* __restrict__ bias,            // b1 [ND,1024]
            const int2* __restrict__ meta,
            unsigned short* __restrict__ H,            // [MPAD,1024]
            float2* __restrict__ stats) {              // [8][MPAD]
    const int2 md = meta[blockIdx.x];
    const int dom = md.x;
    if (dom < 0) return;
    const int m0 = md.y;
    const int n0 = blockIdx.y * 256;

    __shared__ unsigned short As[128 * 32];   //  8 KB
    __shared__ unsigned short Bs[256 * 32];   // 16 KB

    const int tid = threadIdx.x;
    const int lane = tid & 63;
    const int w = tid >> 6;
    const int wr = w >> 1, wc = w & 1;
    const int c16 = lane & 15, quad = lane >> 4;

    const unsigned short* Abase = A + (size_t)m0 * DIN;
    const unsigned short* Bbase = Bt + (size_t)dom * DHID * DIN + (size_t)n0 * DIN;

    floatx4 acc[4][8];
#pragma unroll
    for (int i = 0; i < 4; i++)
#pragma unroll
        for (int j = 0; j < 8; j++) acc[i][j] = 0.f;

    for (int k0 = 0; k0 < DIN; k0 += 32) {
#pragma unroll
        for (int it = 0; it < 2; ++it) {               // A: 512 chunks
            const int c = w * 128 + it * 64 + lane;
            const int m = c >> 2, kc = c & 3;
            GLDS16(Abase + (size_t)m * DIN + k0 + kc * 8, &As[(w * 128 + it * 64) * 8]);
        }
#pragma unroll
        for (int it = 0; it < 4; ++it) {               // B: 1024 chunks
            const int c = w * 256 + it * 64 + lane;
            const int n = c >> 2, kc = c & 3;
            GLDS16(Bbase + (size_t)n * DIN + k0 + kc * 8, &Bs[(w * 256 + it * 64) * 8]);
        }
        __syncthreads();

        short8 a[4], b[8];
        const int kk = quad * 8;
#pragma unroll
        for (int i = 0; i < 4; i++)
            a[i] = *(const short8*)&As[(wr * 64 + i * 16 + c16) * 32 + kk];
#pragma unroll
        for (int j = 0; j < 8; j++)
            b[j] = *(const short8*)&Bs[(wc * 128 + j * 16 + c16) * 32 + kk];
#pragma unroll
        for (int i = 0; i < 4; i++)
#pragma unroll
            for (int j = 0; j < 8; j++)
                acc[i][j] = __builtin_amdgcn_mfma_f32_16x16x32_bf16(a[i], b[j], acc[i][j], 0, 0, 0);
        __syncthreads();
    }

    float bv[8];
#pragma unroll
    for (int j = 0; j < 8; j++)
        bv[j] = bias[dom * DHID + n0 + wc * 128 + j * 16 + c16];

    float2* st = stats + (size_t)(blockIdx.y * 2 + wc) * MPAD;
#pragma unroll
    for (int i = 0; i < 4; i++) {
        const int rowbase = m0 + wr * 64 + i * 16 + quad * 4;
#pragma unroll
        for (int r = 0; r < 4; r++) {
            float s = 0.f, q = 0.f;
            unsigned short* hrow = H + (size_t)(rowbase + r) * DHID + n0 + wc * 128;
#pragma unroll
            for (int j = 0; j < 8; j++) {
                const float v = acc[i][j][r] + bv[j];
                hrow[j * 16 + c16] = f2bf(v);
                s += v; q += v * v;
            }
#pragma unroll
            for (int o = 1; o < 16; o <<= 1) {   // reduce across 16 col lanes
                s += __shfl_xor(s, o, 64);
                q += __shfl_xor(q, o, 64);
            }
            if (c16 == 0) st[rowbase + r] = make_float2(s, q);
        }
    }
}

// ---------------- 4. GEMM-B (full 256 cols) with LN+ReLU in A-staging --------
__global__ __launch_bounds__(256, 1)
void gemm_b_ln(const unsigned short* __restrict__ H,   // [MPAD,1024] raw h+b1
               const unsigned short* __restrict__ Bt,  // W2T [ND,256,1024]
               const float* __restrict__ bias,         // b2 [ND,256]
               const float* __restrict__ gamma,
               const float* __restrict__ beta,
               const float2* __restrict__ stats,       // [8][MPAD]
               const int2* __restrict__ meta,
               const int* __restrict__ perm,
               float* __restrict__ out) {
    const int2 md = meta[blockIdx.x];
    const int dom = md.x;
    if (dom < 0) return;
    const int m0 = md.y;

    __shared__ unsigned short As[128 * 32];    //  8 KB
    __shared__ unsigned short Bs[256 * 32];    // 16 KB
    __shared__ unsigned short gsh[DHID];       //  2 KB bf16 gamma
    __shared__ unsigned short bsh[DHID];       //  2 KB bf16 beta
    __shared__ float mu_s[128], rs_s[128];

    const int tid = threadIdx.x;
    const int lane = tid & 63;
    const int w = tid >> 6;
    const int wr = w >> 1, wc = w & 1;
    const int c16 = lane & 15, quad = lane >> 4;

    // prologue: per-row LN constants + gamma/beta -> LDS (bf16)
    if (tid < 128) {
        float s = 0.f, q = 0.f;
#pragma unroll
        for (int cb = 0; cb < 8; cb++) {
            const float2 p = stats[(size_t)cb * MPAD + m0 + tid];
            s += p.x; q += p.y;
        }
        const float inv = 1.0f / (float)DHID;
        const float mu = s * inv;
        const float var = fmaxf(q * inv - mu * mu, 0.f);
        mu_s[tid] = mu;
        rs_s[tid] = rsqrtf(var + 1e-5f);
    }
    {
        const int base = tid * 4;
        const float4 g4 = *(const float4*)(gamma + dom * DHID + base);
        const float4 b4 = *(const float4*)(beta + dom * DHID + base);
        gsh[base + 0] = f2bf(g4.x); gsh[base + 1] = f2bf(g4.y);
        gsh[base + 2] = f2bf(g4.z); gsh[base + 3] = f2bf(g4.w);
        bsh[base + 0] = f2bf(b4.x); bsh[base + 1] = f2bf(b4.y);
        bsh[base + 2] = f2bf(b4.z); bsh[base + 3] = f2bf(b4.w);
    }
    __syncthreads();

    const unsigned short* Hbase = H + (size_t)m0 * DHID;
    const unsigned short* Bbase = Bt + (size_t)dom * DOUT * DHID;

    floatx4 acc[4][8];
#pragma unroll
    for (int i = 0; i < 4; i++)
#pragma unroll
        for (int j = 0; j < 8; j++) acc[i][j] = 0.f;

    // H prefetch one K-step ahead (latency hides behind the B-GLDS barrier drain)
    const int c0i = tid, c1i = 256 + tid;
    const int row0 = c0i >> 2, kg0 = c0i & 3;
    const int row1 = c1i >> 2, kg1 = c1i & 3;
    ushort8v hv0 = *(const ushort8v*)(Hbase + (size_t)row0 * DHID + kg0 * 8);
    ushort8v hv1 = *(const ushort8v*)(Hbase + (size_t)row1 * DHID + kg1 * 8);

    for (int k0 = 0; k0 < DHID; k0 += 32) {
        // ---- A: transform prefetched H -> LDS (LN * gamma + beta, ReLU) ----
        {
            const float mu0 = mu_s[row0], rs0 = rs_s[row0];
            const float mu1 = mu_s[row1], rs1 = rs_s[row1];
            const ushort8v g0 = *(const ushort8v*)&gsh[k0 + kg0 * 8];
            const ushort8v b0 = *(const ushort8v*)&bsh[k0 + kg0 * 8];
            const ushort8v g1 = *(const ushort8v*)&gsh[k0 + kg1 * 8];
            const ushort8v b1v = *(const ushort8v*)&bsh[k0 + kg1 * 8];
            ushort8v o0, o1;
#pragma unroll
            for (int e = 0; e < 8; e++) {
                const float t0 = (bf2f(hv0[e]) - mu0) * rs0;
                o0[e] = f2bf(fmaxf(t0 * bf2f(g0[e]) + bf2f(b0[e]), 0.f));
                const float t1 = (bf2f(hv1[e]) - mu1) * rs1;
                o1[e] = f2bf(fmaxf(t1 * bf2f(g1[e]) + bf2f(b1v[e]), 0.f));
            }
            *(ushort8v*)&As[row0 * 32 + kg0 * 8] = o0;
            *(ushort8v*)&As[row1 * 32 + kg1 * 8] = o1;
        }
        // ---- B: GLDS16, 1024 chunks ----
#pragma unroll
        for (int it = 0; it < 4; ++it) {
            const int c = w * 256 + it * 64 + lane;
            const int n = c >> 2, kc = c & 3;
            GLDS16(Bbase + (size_t)n * DHID + k0 + kc * 8, &Bs[(w * 256 + it * 64) * 8]);
        }
        // ---- prefetch next H chunk ----
        if (k0 + 32 < DHID) {
            hv0 = *(const ushort8v*)(Hbase + (size_t)row0 * DHID + k0 + 32 + kg0 * 8);
            hv1 = *(const ushort8v*)(Hbase + (size_t)row1 * DHID + k0 + 32 + kg1 * 8);
        }
        __syncthreads();

        short8 a[4], b[8];
        const int kk = quad * 8;
#pragma unroll
        for (int i = 0; i < 4; i++)
            a[i] = *(const short8*)&As[(wr * 64 + i * 16 + c16) * 32 + kk];
#pragma unroll
        for (int j = 0; j < 8; j++)
            b[j] = *(const short8*)&Bs[(wc * 128 + j * 16 + c16) * 32 + kk];
#pragma unroll
        for (int i = 0; i < 4; i++)
#pragma unroll
            for (int j = 0; j < 8; j++)
                acc[i][j] = __builtin_amdgcn_mfma_f32_16x16x32_bf16(a[i], b[j], acc[i][j], 0, 0, 0);
        __syncthreads();
    }

    // epilogue: scatter through perm (C/D layout col=lane&15, row=quad*4+reg)
    float bv[8];
#pragma unroll
    for (int j = 0; j < 8; j++)
        bv[j] = bias[dom * DOUT + wc * 128 + j * 16 + c16];
#pragma unroll
    for (int i = 0; i < 4; i++) {
        const int rowbase = m0 + wr * 64 + i * 16 + quad * 4;
#pragma unroll
        for (int r = 0; r < 4; r++) {
            const int orig = perm[rowbase + r];
            if (orig < 0) continue;     // padding row
#pragma unroll
            for (int j = 0; j < 8; j++) {
                const int col = wc * 128 + j * 16 + c16;
                out[(size_t)orig * DOUT + col] = acc[i][j][r] + bv[j];
            }
        }
    }
}

// ---------------- launch ------------------------------------------------------
extern "C" void kernel_launch(void* const* d_in, const int* in_sizes, int n_in,
                              void* d_out, int out_size, void* d_ws, size_t ws_size,
                              hipStream_t stream) {
    const float* x = (const float*)d_in[0];
    const int* dt = (const int*)d_in[1];
    const float* W1 = (const float*)d_in[2];
    const float* b1 = (const float*)d_in[3];
    const float* gamma = (const float*)d_in[4];
    const float* beta = (const float*)d_in[5];
    const float* W2 = (const float*)d_in[6];
    const float* b2 = (const float*)d_in[7];
    float* out = (float*)d_out;

    char* ws = (char*)d_ws;
    size_t off = 0;
    auto take = [&](size_t nbytes) -> char* {
        char* p = ws + off;
        off = (off + nbytes + 255) & ~(size_t)255;
        return p;
    };
    unsigned short* W1T = (unsigned short*)take((size_t)ND * DHID * DIN * 2);
    unsigned short* W2T = (unsigned short*)take((size_t)ND * DOUT * DHID * 2);
    unsigned short* XS  = (unsigned short*)take((size_t)MPAD * DIN * 2);
    unsigned short* H   = (unsigned short*)take((size_t)MPAD * DHID * 2);
    float2* STATS = (float2*)take((size_t)8 * MPAD * 8);
    int* PERM   = (int*)take(MPAD * 4);
    int* POS    = (int*)take(NROWS * 4);
    int* CNT    = (int*)take(64);            // counts[8] then cursors[8]
    int2* META  = (int2*)take(NTILES * 8);
    (void)ws_size; (void)n_in; (void)in_sizes; (void)out_size;

    int* COUNTS = CNT;
    int* CURSORS = CNT + 8;

    transpose_both<<<dim3(8, 32, 16), 256, 0, stream>>>(W1, W2, W1T, W2T, CNT);
    histo<<<NROWS / 256, 256, 0, stream>>>(dt, COUNTS);
    make_meta<<<1, 256, 0, stream>>>(COUNTS, CURSORS, META, PERM);
    assign_pos<<<NROWS / 256, 256, 0, stream>>>(dt, CURSORS, PERM, POS);
    copy_rows<<<NROWS / 4, 256, 0, stream>>>(x, POS, XS);
    gemm_a<<<dim3(NTILES, 4), 256, 0, stream>>>(XS, W1T, b1, META, H, STATS);
    gemm_b_ln<<<NTILES, 256, 0, stream>>>(
        H, W2T, b2, gamma, beta, STATS, META, PERM, out);
}

// Round 6
// 228.810 us; speedup vs baseline: 1.0789x; 1.0789x over previous
//
#include <hip/hip_runtime.h>
#include <hip/hip_bf16.h>

// DomainEncoder: 8-expert MoE MLP, N=32768, 256 -> 1024 (LN+ReLU) -> 256.
// Pipeline (6 kernels + 1 memset):
//   0. hipMemsetAsync: zero sort counters (graph-safe)
//   1. transpose_histo: W1,W2 -> bf16 [N,K] (z<16) + domain histogram (z==16)
//   2. make_meta: offsets + 128-row tile metadata + perm padding
//   3. assign_copy: per-block position assignment (8 global atomics/block)
//      fused with the coalesced x->bf16 gather copy
//   4. gemm_a: 128x256 blocks, H = x_s @ W1[d]^T + b1 (bf16) + stats[8][MPAD]
//   5. ln_relu: H = ReLU(LN(H)*gamma+beta) in place, stats-based (no reduction),
//      gamma/beta in registers (fixed cols per thread)
//   6. gemm_bt: plain m97 128x128, out = g @ W2[d]^T + b2, scatter via perm
// Lesson from R3/R4/R5: LN fused into GEMM-B A-staging loses 30-50us every
// time (barrier-exposed transform, occupancy loss). Plain GEMM + BW-bound LN
// pass wins.

#define ND 8
#define NROWS 32768
#define DIN 256
#define DHID 1024
#define DOUT 256
#define MPAD 33792          // 32768 + 8*128 worst-case padding
#define NTILES 264          // 256 + 8 worst-case 128-row tiles

typedef short short8 __attribute__((ext_vector_type(8)));
typedef unsigned short ushort8v __attribute__((ext_vector_type(8)));
typedef float floatx4 __attribute__((ext_vector_type(4)));

__device__ __forceinline__ unsigned short f2bf(float f) {
    unsigned u = __builtin_bit_cast(unsigned, f);
    unsigned r = u + 0x7fff + ((u >> 16) & 1);   // RNE (inputs finite)
    return (unsigned short)(r >> 16);
}
__device__ __forceinline__ float bf2f(unsigned short h) {
    unsigned u = ((unsigned)h) << 16;
    return __builtin_bit_cast(float, u);
}

#define GLDS16(gp, lp) __builtin_amdgcn_global_load_lds( \
    (const __attribute__((address_space(1))) void*)(gp), \
    (__attribute__((address_space(3))) void*)(lp), 16, 0, 0)

// ---------------- 1. weight transposes + histogram in one launch -------------
// grid dim3(8,32,17): z<8 -> W1 dom z; z in 8..15 -> W2 dom z-8; z==16 -> histo
__global__ void transpose_histo(const float* __restrict__ W1,
                                const float* __restrict__ W2,
                                unsigned short* __restrict__ W1T,
                                unsigned short* __restrict__ W2T,
                                const int* __restrict__ dt,
                                int* __restrict__ counts) {
    const int z = blockIdx.z;
    if (z == 16) {                       // histogram slice
        const int bid = blockIdx.y * 8 + blockIdx.x;
        if (bid >= NROWS / 256) return;
        __shared__ int lc[ND];
        if (threadIdx.x < ND) lc[threadIdx.x] = 0;
        __syncthreads();
        atomicAdd(&lc[dt[bid * 256 + threadIdx.x]], 1);
        __syncthreads();
        if (threadIdx.x < ND) atomicAdd(&counts[threadIdx.x], lc[threadIdx.x]);
        return;
    }
    __shared__ float t[32][33];
    const bool isW1 = z < ND;
    const int d = isW1 ? z : z - ND;
    const int R = isW1 ? DIN : DHID;
    const int C = isW1 ? DHID : DOUT;
    const int r0 = (isW1 ? blockIdx.x : blockIdx.y) * 32;
    const int c0 = (isW1 ? blockIdx.y : blockIdx.x) * 32;
    const int tx = threadIdx.x & 31, ty = threadIdx.x >> 5;   // 32x8
    const float* src = (isW1 ? W1 : W2) + (size_t)d * R * C;
    unsigned short* dst = (isW1 ? W1T : W2T) + (size_t)d * R * C;
#pragma unroll
    for (int i = 0; i < 32; i += 8)
        t[ty + i][tx] = src[(size_t)(r0 + ty + i) * C + c0 + tx];
    __syncthreads();
#pragma unroll
    for (int i = 0; i < 32; i += 8)
        dst[(size_t)(c0 + ty + i) * R + r0 + tx] = f2bf(t[tx][ty + i]);
}

// ---------------- 2. offsets + tile metadata + parallel perm pad -------------
__global__ void make_meta(const int* __restrict__ counts, int* __restrict__ cursors,
                          int2* __restrict__ meta, int* __restrict__ perm) {
    __shared__ int ps[ND], pe[ND];
    if (threadIdx.x == 0) {
        int off = 0, t = 0;
        for (int d = 0; d < ND; d++) {
            cursors[d] = off;
            int nt = (counts[d] + 127) >> 7;
            for (int i = 0; i < nt; i++) meta[t++] = make_int2(d, off + (i << 7));
            ps[d] = off + counts[d];
            pe[d] = off + (nt << 7);
            off += nt << 7;
        }
        for (; t < NTILES; t++) meta[t] = make_int2(-1, 0);
    }
    __syncthreads();
#pragma unroll
    for (int d = 0; d < ND; d++)
        for (int p = ps[d] + threadIdx.x; p < pe[d]; p += 256) perm[p] = -1;
}

// ---------------- 3. position assignment fused with gather copy --------------
__global__ __launch_bounds__(256)
void assign_copy(const float* __restrict__ x, const int* __restrict__ dt,
                 int* __restrict__ cursors, int* __restrict__ perm,
                 unsigned short* __restrict__ xs) {
    __shared__ int lcnt[ND], lbase[ND];
    __shared__ int spos[256];
    const int tid = threadIdx.x;
    if (tid < ND) lcnt[tid] = 0;
    __syncthreads();
    const int r = blockIdx.x * 256 + tid;
    const int d = dt[r];
    const int myrank = atomicAdd(&lcnt[d], 1);   // LDS atomic: cheap
    __syncthreads();
    if (tid < ND && lcnt[tid] > 0)
        lbase[tid] = atomicAdd(&cursors[tid], lcnt[tid]);  // 8 global atomics/block
    __syncthreads();
    const int p = lbase[d] + myrank;
    spos[tid] = p;
    perm[p] = r;
    __syncthreads();
    // copy phase: 4 rows per iteration, float4/lane (fully coalesced)
    const int lane = tid & 63;
    const int sub = tid >> 6;
    for (int it = 0; it < 64; ++it) {
        const int lr = it * 4 + sub;
        const int gr = blockIdx.x * 256 + lr;
        const int pp = spos[lr];
        float4 v = ((const float4*)(x + (size_t)gr * DIN))[lane];
        ushort4 o;
        o.x = f2bf(v.x); o.y = f2bf(v.y); o.z = f2bf(v.z); o.w = f2bf(v.w);
        ((ushort4*)(xs + (size_t)pp * DIN))[lane] = o;
    }
}

// ---------------- 4. GEMM-A: 128x256 block, bias + per-row stats -------------
// 4 waves in 2x2; wave tile 64 rows x 128 cols = 4x8 mfma_16x16x32_bf16.
// stats slab = blockIdx.y*2 + wc (8 slabs); each slot written exactly once.
__global__ __launch_bounds__(256, 2)
void gemm_a(const unsigned short* __restrict__ A,      // XS [MPAD,256]
            const unsigned short* __restrict__ Bt,     // W1T [ND,1024,256]
            const float* __restrict__ bias,            // b1 [ND,1024]
            const int2* __restrict__ meta,
            unsigned short* __restrict__ H,            // [MPAD,1024]
            float2* __restrict__ stats) {              // [8][MPAD]
    const int2 md = meta[blockIdx.x];
    const int dom = md.x;
    if (dom < 0) return;
    const int m0 = md.y;
    const int n0 = blockIdx.y * 256;

    __shared__ unsigned short As[128 * 32];   //  8 KB
    __shared__ unsigned short Bs[256 * 32];   // 16 KB

    const int tid = threadIdx.x;
    const int lane = tid & 63;
    const int w = tid >> 6;
    const int wr = w >> 1, wc = w & 1;
    const int c16 = lane & 15, quad = lane >> 4;

    const unsigned short* Abase = A + (size_t)m0 * DIN;
    const unsigned short* Bbase = Bt + (size_t)dom * DHID * DIN + (size_t)n0 * DIN;

    floatx4 acc[4][8];
#pragma unroll
    for (int i = 0; i < 4; i++)
#pragma unroll
        for (int j = 0; j < 8; j++) acc[i][j] = 0.f;

    for (int k0 = 0; k0 < DIN; k0 += 32) {
#pragma unroll
        for (int it = 0; it < 2; ++it) {               // A: 512 chunks
            const int c = w * 128 + it * 64 + lane;
            const int m = c >> 2, kc = c & 3;
            GLDS16(Abase + (size_t)m * DIN + k0 + kc * 8, &As[(w * 128 + it * 64) * 8]);
        }
#pragma unroll
        for (int it = 0; it < 4; ++it) {               // B: 1024 chunks
            const int c = w * 256 + it * 64 + lane;
            const int n = c >> 2, kc = c & 3;
            GLDS16(Bbase + (size_t)n * DIN + k0 + kc * 8, &Bs[(w * 256 + it * 64) * 8]);
        }
        __syncthreads();

        short8 a[4], b[8];
        const int kk = quad * 8;
#pragma unroll
        for (int i = 0; i < 4; i++)
            a[i] = *(const short8*)&As[(wr * 64 + i * 16 + c16) * 32 + kk];
#pragma unroll
        for (int j = 0; j < 8; j++)
            b[j] = *(const short8*)&Bs[(wc * 128 + j * 16 + c16) * 32 + kk];
#pragma unroll
        for (int i = 0; i < 4; i++)
#pragma unroll
            for (int j = 0; j < 8; j++)
                acc[i][j] = __builtin_amdgcn_mfma_f32_16x16x32_bf16(a[i], b[j], acc[i][j], 0, 0, 0);
        __syncthreads();
    }

    float bv[8];
#pragma unroll
    for (int j = 0; j < 8; j++)
        bv[j] = bias[dom * DHID + n0 + wc * 128 + j * 16 + c16];

    float2* st = stats + (size_t)(blockIdx.y * 2 + wc) * MPAD;
#pragma unroll
    for (int i = 0; i < 4; i++) {
        const int rowbase = m0 + wr * 64 + i * 16 + quad * 4;
#pragma unroll
        for (int r = 0; r < 4; r++) {
            float s = 0.f, q = 0.f;
            unsigned short* hrow = H + (size_t)(rowbase + r) * DHID + n0 + wc * 128;
#pragma unroll
            for (int j = 0; j < 8; j++) {
                const float v = acc[i][j][r] + bv[j];
                hrow[j * 16 + c16] = f2bf(v);
                s += v; q += v * v;
            }
#pragma unroll
            for (int o = 1; o < 16; o <<= 1) {   // reduce across 16 col lanes
                s += __shfl_xor(s, o, 64);
                q += __shfl_xor(q, o, 64);
            }
            if (c16 == 0) st[rowbase + r] = make_float2(s, q);
        }
    }
}

// ---------------- 5. LayerNorm+ReLU in place, stats-based --------------------
// Block = 32 rows. Thread t owns cols [ (t&127)*8, +8 ) for all 32 rows ->
// gamma/beta live in 16 registers, loaded once. 16 iters x 2 rows,
// 16B/lane coalesced global access. Pure BW: 132 MB round trip.
__global__ __launch_bounds__(256)
void ln_relu(unsigned short* __restrict__ H,
             const float* __restrict__ gamma, const float* __restrict__ beta,
             const float2* __restrict__ stats, const int2* __restrict__ meta) {
    const int2 md = meta[blockIdx.x >> 2];
    const int dom = md.x;
    if (dom < 0) return;
    const int m0 = md.y + (blockIdx.x & 3) * 32;

    __shared__ float mu_s[32], rs_s[32];
    const int tid = threadIdx.x;
    if (tid < 32) {
        float s = 0.f, q = 0.f;
#pragma unroll
        for (int cb = 0; cb < 8; cb++) {
            const float2 p = stats[(size_t)cb * MPAD + m0 + tid];
            s += p.x; q += p.y;
        }
        const float inv = 1.0f / (float)DHID;
        const float mu = s * inv;
        const float var = fmaxf(q * inv - mu * mu, 0.f);
        mu_s[tid] = mu;
        rs_s[tid] = rsqrtf(var + 1e-5f);
    }
    const int cc = (tid & 127) * 8;
    const float4 g0 = *(const float4*)(gamma + dom * DHID + cc);
    const float4 g1 = *(const float4*)(gamma + dom * DHID + cc + 4);
    const float4 b0 = *(const float4*)(beta + dom * DHID + cc);
    const float4 b1 = *(const float4*)(beta + dom * DHID + cc + 4);
    const float gg[8] = {g0.x, g0.y, g0.z, g0.w, g1.x, g1.y, g1.z, g1.w};
    const float bb[8] = {b0.x, b0.y, b0.z, b0.w, b1.x, b1.y, b1.z, b1.w};
    __syncthreads();

    const int half = tid >> 7;           // 0/1: two rows per iteration
#pragma unroll 4
    for (int it = 0; it < 16; ++it) {
        const int lr = it * 2 + half;
        unsigned short* hp = H + (size_t)(m0 + lr) * DHID + cc;
        const ushort8v hv = *(const ushort8v*)hp;
        const float mu = mu_s[lr], rs = rs_s[lr];
        ushort8v o;
#pragma unroll
        for (int e = 0; e < 8; e++)
            o[e] = f2bf(fmaxf((bf2f(hv[e]) - mu) * rs * gg[e] + bb[e], 0.f));
        *(ushort8v*)hp = o;
    }
}

// ---------------- 6. GEMM-B plain m97 128x128, scatter epilogue --------------
__global__ __launch_bounds__(256, 2)
void gemm_bt(const unsigned short* __restrict__ A,      // H' [MPAD,1024]
             const unsigned short* __restrict__ Bt,     // W2T [ND,256,1024]
             const float* __restrict__ bias,            // b2 [ND,256]
             const int2* __restrict__ meta,
             const int* __restrict__ perm,
             float* __restrict__ out) {
    const int2 md = meta[blockIdx.x];
    const int dom = md.x;
    if (dom < 0) return;
    const int m0 = md.y;
    const int n0 = blockIdx.y * 128;

    __shared__ unsigned short As[128 * 32];   // 8 KB
    __shared__ unsigned short Bs[128 * 32];   // 8 KB

    const int tid = threadIdx.x;
    const int lane = tid & 63;
    const int w = tid >> 6;
    const int wr = w >> 1, wc = w & 1;
    const int c16 = lane & 15, quad = lane >> 4;

    const unsigned short* Abase = A + (size_t)m0 * DHID;
    const unsigned short* Bbase = Bt + (size_t)dom * DOUT * DHID + (size_t)n0 * DHID;

    floatx4 acc[4][4];
#pragma unroll
    for (int i = 0; i < 4; i++)
#pragma unroll
        for (int j = 0; j < 4; j++) acc[i][j] = 0.f;

    for (int k0 = 0; k0 < DHID; k0 += 32) {
#pragma unroll
        for (int it = 0; it < 2; ++it) {
            const int c = w * 128 + it * 64 + lane;
            const int m = c >> 2, kc = c & 3;
            GLDS16(Abase + (size_t)m * DHID + k0 + kc * 8, &As[(w * 128 + it * 64) * 8]);
            GLDS16(Bbase + (size_t)m * DHID + k0 + kc * 8, &Bs[(w * 128 + it * 64) * 8]);
        }
        __syncthreads();

        short8 a[4], b[4];
        const int kk = quad * 8;
#pragma unroll
        for (int i = 0; i < 4; i++) {
            a[i] = *(const short8*)&As[(wr * 64 + i * 16 + c16) * 32 + kk];
            b[i] = *(const short8*)&Bs[(wc * 64 + i * 16 + c16) * 32 + kk];
        }
#pragma unroll
        for (int i = 0; i < 4; i++)
#pragma unroll
            for (int j = 0; j < 4; j++)
                acc[i][j] = __builtin_amdgcn_mfma_f32_16x16x32_bf16(a[i], b[j], acc[i][j], 0, 0, 0);
        __syncthreads();
    }

    // epilogue: scatter through perm (C/D layout col=lane&15, row=quad*4+reg)
#pragma unroll
    for (int i = 0; i < 4; i++) {
        const int rowbase = m0 + wr * 64 + i * 16 + quad * 4;
#pragma unroll
        for (int r = 0; r < 4; r++) {
            const int orig = perm[rowbase + r];
            if (orig < 0) continue;     // padding row
#pragma unroll
            for (int j = 0; j < 4; j++) {
                const int col = n0 + wc * 64 + j * 16 + c16;
                out[(size_t)orig * DOUT + col] = acc[i][j][r] + bias[dom * DOUT + col];
            }
        }
    }
}

// ---------------- launch ------------------------------------------------------
extern "C" void kernel_launch(void* const* d_in, const int* in_sizes, int n_in,
                              void* d_out, int out_size, void* d_ws, size_t ws_size,
                              hipStream_t stream) {
    const float* x = (const float*)d_in[0];
    const int* dt = (const int*)d_in[1];
    const float* W1 = (const float*)d_in[2];
    const float* b1 = (const float*)d_in[3];
    const float* gamma = (const float*)d_in[4];
    const float* beta = (const float*)d_in[5];
    const float* W2 = (const float*)d_in[6];
    const float* b2 = (const float*)d_in[7];
    float* out = (float*)d_out;

    char* ws = (char*)d_ws;
    size_t off = 0;
    auto take = [&](size_t nbytes) -> char* {
        char* p = ws + off;
        off = (off + nbytes + 255) & ~(size_t)255;
        return p;
    };
    unsigned short* W1T = (unsigned short*)take((size_t)ND * DHID * DIN * 2);
    unsigned short* W2T = (unsigned short*)take((size_t)ND * DOUT * DHID * 2);
    unsigned short* XS  = (unsigned short*)take((size_t)MPAD * DIN * 2);
    unsigned short* H   = (unsigned short*)take((size_t)MPAD * DHID * 2);
    float2* STATS = (float2*)take((size_t)8 * MPAD * 8);
    int* PERM   = (int*)take(MPAD * 4);
    int* CNT    = (int*)take(64);            // counts[8] then cursors[8]
    int2* META  = (int2*)take(NTILES * 8);
    (void)ws_size; (void)n_in; (void)in_sizes; (void)out_size;

    int* COUNTS = CNT;
    int* CURSORS = CNT + 8;

    hipMemsetAsync(CNT, 0, 64, stream);      // graph-safe (stream-ordered)
    transpose_histo<<<dim3(8, 32, 17), 256, 0, stream>>>(W1, W2, W1T, W2T, dt, COUNTS);
    make_meta<<<1, 256, 0, stream>>>(COUNTS, CURSORS, META, PERM);
    assign_copy<<<NROWS / 256, 256, 0, stream>>>(x, dt, CURSORS, PERM, XS);
    gemm_a<<<dim3(NTILES, 4), 256, 0, stream>>>(XS, W1T, b1, META, H, STATS);
    ln_relu<<<NTILES * 4, 256, 0, stream>>>(H, gamma, beta, STATS, META);
    gemm_bt<<<dim3(NTILES, 2), 256, 0, stream>>>(H, W2T, b2, META, PERM, out);
}